// Round 1
// baseline (253.618 us; speedup 1.0000x reference)
//
#include <hip/hip_runtime.h>
#include <hip/hip_bf16.h>

// DilatedAttention (b=4, n=8192, d=1024, w=2048, r=4):
// 16 independent 512x512 self-attentions at d=1024 over gathered tokens
// off + 4*j per segment. alphas==1 (idx unique), so output = scatter(att).
//
// Pipeline: gather(x->xg,xgT bf16) ; QK GEMM -> S ; rowwise softmax ;
// PV GEMM -> nontemporal scatter store + fused zero-fill.
//
// R1 change: QK and PV GEMMs get double-buffered LDS with the minimum
// 2-phase schedule (stage t+1 BEFORE computing t, single vmcnt(0)+barrier
// per K-step) + bijective XCD-chunk blockIdx swizzle (512%8==0) so each
// XCD's L2 holds only its 2 segments' panels.

typedef __bf16 bf16_t;
typedef __bf16 bf16x8 __attribute__((ext_vector_type(8)));
typedef float floatx4 __attribute__((ext_vector_type(4)));

#define D_MODEL 1024
#define SEG_W   2048
#define RATE    4
#define M_SUB   512          // tokens per segment after dilation (w/r)
#define NTOK    8192
#define NSEGT   16           // batch(4) * segments(4)
#define XG_ELEMS ((long)NSEGT * M_SUB * D_MODEL)

__device__ __forceinline__ void gload16(const bf16_t* g, bf16_t* l) {
    __builtin_amdgcn_global_load_lds(
        (const __attribute__((address_space(1))) void*)g,
        (__attribute__((address_space(3))) void*)l, 16, 0, 0);
}

// ---------------------------------------------------------------------------
// K1: gather x[b, s*2048 + off + 4i, :] -> xg bf16 [seg][i][d]
//                                       -> xgT bf16 [seg][d][i]
// ---------------------------------------------------------------------------
__global__ __launch_bounds__(256) void gather_kernel(
    const float* __restrict__ x, const int* __restrict__ hidp,
    bf16_t* __restrict__ xg, bf16_t* __restrict__ xgT)
{
    const int off = ((hidp[0] % RATE) + RATE) % RATE;
    const int bid = blockIdx.x;
    const int seg = bid >> 7;          // 0..15
    const int rem = bid & 127;
    const int it  = rem >> 4;          // i-tile 0..7
    const int dt  = rem & 15;          // d-tile 0..15
    const int b   = seg >> 2, s = seg & 3;

    __shared__ ushort tile[64][65];

    const int t  = threadIdx.x;
    const int r  = t >> 2;             // 0..63
    const int cq = (t & 3) << 4;       // 0,16,32,48

    union U8 { bf16x8 v; ushort u[8]; };

    {
        const int  i   = it * 64 + r;
        const long tok = (long)s * SEG_W + off + 4L * i;
        const float* src = x + ((long)b * NTOK + tok) * D_MODEL + dt * 64 + cq;
        float4 f0 = ((const float4*)src)[0];
        float4 f1 = ((const float4*)src)[1];
        float4 f2 = ((const float4*)src)[2];
        float4 f3 = ((const float4*)src)[3];
        U8 lo, hi;
        lo.v[0]=(bf16_t)f0.x; lo.v[1]=(bf16_t)f0.y; lo.v[2]=(bf16_t)f0.z; lo.v[3]=(bf16_t)f0.w;
        lo.v[4]=(bf16_t)f1.x; lo.v[5]=(bf16_t)f1.y; lo.v[6]=(bf16_t)f1.z; lo.v[7]=(bf16_t)f1.w;
        hi.v[0]=(bf16_t)f2.x; hi.v[1]=(bf16_t)f2.y; hi.v[2]=(bf16_t)f2.z; hi.v[3]=(bf16_t)f2.w;
        hi.v[4]=(bf16_t)f3.x; hi.v[5]=(bf16_t)f3.y; hi.v[6]=(bf16_t)f3.z; hi.v[7]=(bf16_t)f3.w;
        bf16_t* dstg = xg + ((long)seg * M_SUB + i) * D_MODEL + dt * 64 + cq;
        *(bf16x8*)(dstg)     = lo.v;
        *(bf16x8*)(dstg + 8) = hi.v;
        #pragma unroll
        for (int j = 0; j < 8; ++j) { tile[r][cq + j] = lo.u[j]; tile[r][cq + 8 + j] = hi.u[j]; }
    }
    __syncthreads();
    {
        const int dc = r;
        const int iq = cq;
        U8 o0, o1;
        #pragma unroll
        for (int j = 0; j < 8; ++j) { o0.u[j] = tile[iq + j][dc]; o1.u[j] = tile[iq + 8 + j][dc]; }
        bf16_t* dstT = xgT + ((long)seg * D_MODEL + dt * 64 + dc) * M_SUB + it * 64 + iq;
        *(bf16x8*)(dstT)     = o0.v;
        *(bf16x8*)(dstT + 8) = o1.v;
    }
}

// ---------------------------------------------------------------------------
// K2: QK GEMM. S[seg][q][k] = scale * sum_d xg[q][d]*xg[k][d], bf16 out.
// BM=64, BN=128, BK=64. grid = 512 blocks, 4 waves.
// Double-buffered LDS, 2-phase schedule: stage(t+1) issued before compute(t),
// one vmcnt(0)+barrier (__syncthreads) per K-step -> stage latency hides
// under the 16 MFMAs + ds_reads of the current step.
// XOR chunk swizzle unchanged: chunk c of row r lives at slot c^(r&7).
// ---------------------------------------------------------------------------
__global__ __launch_bounds__(256) void qk_kernel(
    const bf16_t* __restrict__ xg, bf16_t* __restrict__ S)
{
    const int bid0 = blockIdx.x;
    const int bid  = ((bid0 & 7) << 6) | (bid0 >> 3);   // XCD chunk swizzle (bijective, 512%8==0)
    const int seg = bid >> 5;
    const int mt  = (bid >> 2) & 7;
    const int nt  = bid & 3;

    const int tid  = threadIdx.x;
    const int w    = tid >> 6;
    const int lane = tid & 63;
    const int l16  = lane & 15;
    const int quad = lane >> 4;
    const int wr   = w >> 1, wc = w & 1;
    const int rowin = lane >> 3;            // 0..7 row within 8-row round
    const int cswz  = ((lane & 7) ^ rowin) * 8;  // swizzled chunk offset (elems)
    const int rsw   = l16 & 7;              // fragment-row swizzle key

    __shared__ alignas(16) bf16_t As[2][64 * 64];    // 2 x 8 KB
    __shared__ alignas(16) bf16_t Bs[2][128 * 64];   // 2 x 16 KB

    const bf16_t* xseg = xg + (long)seg * M_SUB * D_MODEL;

    const bf16_t* ga0 = xseg + (long)(mt * 64 + w * 16 + rowin) * D_MODEL + cswz;
    const bf16_t* ga1 = ga0 + 8 * D_MODEL;
    const bf16_t* gb0 = xseg + (long)(nt * 128 + w * 32 + rowin) * D_MODEL + cswz;
    const bf16_t* gb1 = gb0 +  8 * D_MODEL;
    const bf16_t* gb2 = gb0 + 16 * D_MODEL;
    const bf16_t* gb3 = gb0 + 24 * D_MODEL;
    const int la0 = (w * 16 + 0) * 64, la1 = (w * 16 + 8) * 64;
    const int lb0 = (w * 32 + 0) * 64, lb1 = (w * 32 + 8) * 64;
    const int lb2 = (w * 32 + 16) * 64, lb3 = (w * 32 + 24) * 64;

    floatx4 acc[2][4];
    #pragma unroll
    for (int i = 0; i < 2; ++i)
        #pragma unroll
        for (int j = 0; j < 4; ++j) acc[i][j] = (floatx4){0.f, 0.f, 0.f, 0.f};

    // prologue: stage tile 0 into buf 0
    gload16(ga0, &As[0][la0]); gload16(ga1, &As[0][la1]);
    gload16(gb0, &Bs[0][lb0]); gload16(gb1, &Bs[0][lb1]);
    gload16(gb2, &Bs[0][lb2]); gload16(gb3, &Bs[0][lb3]);
    __syncthreads();

    for (int t = 0; t < 16; ++t) {
        const int cur = t & 1;
        if (t < 15) {                       // stage t+1 FIRST (overlaps with compute)
            const int kk = (t + 1) * 64;
            const int nx = cur ^ 1;
            gload16(ga0 + kk, &As[nx][la0]); gload16(ga1 + kk, &As[nx][la1]);
            gload16(gb0 + kk, &Bs[nx][lb0]); gload16(gb1 + kk, &Bs[nx][lb1]);
            gload16(gb2 + kk, &Bs[nx][lb2]); gload16(gb3 + kk, &Bs[nx][lb3]);
        }
        const bf16_t* Ab = As[cur];
        const bf16_t* Bb = Bs[cur];
        #pragma unroll
        for (int ks = 0; ks < 2; ++ks) {
            bf16x8 Af[2], Bf[4];
            #pragma unroll
            for (int m2 = 0; m2 < 2; ++m2) {
                const int row = wr * 32 + m2 * 16 + l16;
                Af[m2] = *(const bf16x8*)&Ab[row * 64 + (((ks * 4 + quad) ^ rsw) * 8)];
            }
            #pragma unroll
            for (int n2 = 0; n2 < 4; ++n2) {
                const int row = wc * 64 + n2 * 16 + l16;
                Bf[n2] = *(const bf16x8*)&Bb[row * 64 + (((ks * 4 + quad) ^ rsw) * 8)];
            }
            #pragma unroll
            for (int m2 = 0; m2 < 2; ++m2)
                #pragma unroll
                for (int n2 = 0; n2 < 4; ++n2)
                    acc[m2][n2] = __builtin_amdgcn_mfma_f32_16x16x32_bf16(Af[m2], Bf[n2], acc[m2][n2], 0, 0, 0);
        }
        __syncthreads();                    // vmcnt(0)+lgkmcnt(0)+barrier: next buf ready
    }

    const float scale = 0.03125f;   // 1/sqrt(1024)
    bf16_t* Sseg = S + (long)seg * M_SUB * M_SUB;
    #pragma unroll
    for (int m2 = 0; m2 < 2; ++m2) {
        const int qrow = mt * 64 + wr * 32 + m2 * 16 + quad * 4;
        #pragma unroll
        for (int n2 = 0; n2 < 4; ++n2) {
            const int col = nt * 128 + wc * 64 + n2 * 16 + l16;
            #pragma unroll
            for (int rg = 0; rg < 4; ++rg)
                Sseg[(long)(qrow + rg) * M_SUB + col] = (bf16_t)(acc[m2][n2][rg] * scale);
        }
    }
}

// ---------------------------------------------------------------------------
// K3: row-wise softmax in-place on S (bf16). 1 wave per 512-row.
// ---------------------------------------------------------------------------
__global__ __launch_bounds__(256) void softmax_kernel(bf16_t* __restrict__ S)
{
    const int row  = blockIdx.x * 4 + (threadIdx.x >> 6);
    const int lane = threadIdx.x & 63;
    bf16_t* p = S + (long)row * M_SUB + lane * 8;
    bf16x8 v = *(const bf16x8*)p;
    float f[8];
    #pragma unroll
    for (int j = 0; j < 8; ++j) f[j] = (float)v[j];
    float m = f[0];
    #pragma unroll
    for (int j = 1; j < 8; ++j) m = fmaxf(m, f[j]);
    #pragma unroll
    for (int d = 1; d < 64; d <<= 1) m = fmaxf(m, __shfl_xor(m, d, 64));
    float sum = 0.f;
    #pragma unroll
    for (int j = 0; j < 8; ++j) { f[j] = __expf(f[j] - m); sum += f[j]; }
    #pragma unroll
    for (int d = 1; d < 64; d <<= 1) sum += __shfl_xor(sum, d, 64);
    const float inv = 1.0f / sum;
    #pragma unroll
    for (int j = 0; j < 8; ++j) v[j] = (bf16_t)(f[j] * inv);
    *(bf16x8*)p = v;
}

// ---------------------------------------------------------------------------
// K4: PV GEMM + fused zero-fill. out[tok][d] = sum_k P[q][k]*V[k][d], V^T=xgT.
// BM=BN=128, BK=64. grid = 512 blocks, 4 waves.
// Double-buffered LDS (2x32KB), 2-phase schedule as K2.
// Epilogue: nontemporal result scatter + nontemporal zero of the 3*128
// non-idx token rows in this block's (token-span, column) range.
// ---------------------------------------------------------------------------
__global__ __launch_bounds__(256) void pv_kernel(
    const bf16_t* __restrict__ S, const bf16_t* __restrict__ xgT,
    const int* __restrict__ hidp, float* __restrict__ out)
{
    const int off = ((hidp[0] % RATE) + RATE) % RATE;
    const int bid0 = blockIdx.x;
    const int bid  = ((bid0 & 7) << 6) | (bid0 >> 3);   // XCD chunk swizzle
    const int seg = bid >> 5;
    const int mt  = (bid >> 3) & 3;
    const int nt  = bid & 7;
    const int b   = seg >> 2, s = seg & 3;

    const int tid  = threadIdx.x;
    const int w    = tid >> 6;
    const int lane = tid & 63;
    const int l16  = lane & 15;
    const int quad = lane >> 4;
    const int wr   = w >> 1, wc = w & 1;
    const int rowin = lane >> 3;
    const int cswz  = ((lane & 7) ^ rowin) * 8;
    const int rsw   = l16 & 7;

    __shared__ alignas(16) bf16_t As[2][128 * 64];   // 2 x 16 KB
    __shared__ alignas(16) bf16_t Bs[2][128 * 64];   // 2 x 16 KB

    const bf16_t* Aseg = S   + (long)seg * M_SUB * M_SUB  + (long)mt * 128 * M_SUB;
    const bf16_t* Bseg = xgT + (long)seg * D_MODEL * M_SUB + (long)nt * 128 * M_SUB;

    const bf16_t* ga0 = Aseg + (long)(w * 32 + rowin) * M_SUB + cswz;
    const bf16_t* ga1 = ga0 +  8 * M_SUB;
    const bf16_t* ga2 = ga0 + 16 * M_SUB;
    const bf16_t* ga3 = ga0 + 24 * M_SUB;
    const bf16_t* gb0 = Bseg + (long)(w * 32 + rowin) * M_SUB + cswz;
    const bf16_t* gb1 = gb0 +  8 * M_SUB;
    const bf16_t* gb2 = gb0 + 16 * M_SUB;
    const bf16_t* gb3 = gb0 + 24 * M_SUB;
    const int la0 = (w * 32 + 0) * 64, la1 = (w * 32 + 8) * 64;
    const int la2 = (w * 32 + 16) * 64, la3 = (w * 32 + 24) * 64;

    floatx4 acc[4][4];
    #pragma unroll
    for (int i = 0; i < 4; ++i)
        #pragma unroll
        for (int j = 0; j < 4; ++j) acc[i][j] = (floatx4){0.f, 0.f, 0.f, 0.f};

    // prologue: stage tile 0 into buf 0
    gload16(ga0, &As[0][la0]); gload16(ga1, &As[0][la1]);
    gload16(ga2, &As[0][la2]); gload16(ga3, &As[0][la3]);
    gload16(gb0, &Bs[0][la0]); gload16(gb1, &Bs[0][la1]);
    gload16(gb2, &Bs[0][la2]); gload16(gb3, &Bs[0][la3]);
    __syncthreads();

    for (int t = 0; t < 8; ++t) {
        const int cur = t & 1;
        if (t < 7) {                        // stage t+1 FIRST
            const int kk = (t + 1) * 64;
            const int nx = cur ^ 1;
            gload16(ga0 + kk, &As[nx][la0]); gload16(ga1 + kk, &As[nx][la1]);
            gload16(ga2 + kk, &As[nx][la2]); gload16(ga3 + kk, &As[nx][la3]);
            gload16(gb0 + kk, &Bs[nx][la0]); gload16(gb1 + kk, &Bs[nx][la1]);
            gload16(gb2 + kk, &Bs[nx][la2]); gload16(gb3 + kk, &Bs[nx][la3]);
        }
        const bf16_t* Ab = As[cur];
        const bf16_t* Bb = Bs[cur];
        #pragma unroll
        for (int ks = 0; ks < 2; ++ks) {
            bf16x8 Af[4], Bf[4];
            #pragma unroll
            for (int m2 = 0; m2 < 4; ++m2) {
                const int row = wr * 64 + m2 * 16 + l16;
                Af[m2] = *(const bf16x8*)&Ab[row * 64 + (((ks * 4 + quad) ^ rsw) * 8)];
            }
            #pragma unroll
            for (int n2 = 0; n2 < 4; ++n2) {
                const int row = wc * 64 + n2 * 16 + l16;
                Bf[n2] = *(const bf16x8*)&Bb[row * 64 + (((ks * 4 + quad) ^ rsw) * 8)];
            }
            #pragma unroll
            for (int m2 = 0; m2 < 4; ++m2)
                #pragma unroll
                for (int n2 = 0; n2 < 4; ++n2)
                    acc[m2][n2] = __builtin_amdgcn_mfma_f32_16x16x32_bf16(Af[m2], Bf[n2], acc[m2][n2], 0, 0, 0);
        }
        __syncthreads();
    }

    // ---- result scatter (nontemporal: not re-read)
    float* obase = out + (long)b * NTOK * D_MODEL;
    #pragma unroll
    for (int m2 = 0; m2 < 4; ++m2) {
        const int qrow0 = mt * 128 + wr * 64 + m2 * 16 + quad * 4;
        #pragma unroll
        for (int rg = 0; rg < 4; ++rg) {
            const long tok = (long)s * SEG_W + off + 4L * (qrow0 + rg);
            float* orow = obase + tok * D_MODEL;
            #pragma unroll
            for (int n2 = 0; n2 < 4; ++n2) {
                const int d = nt * 128 + wc * 64 + n2 * 16 + l16;
                __builtin_nontemporal_store(acc[m2][n2][rg], &orow[d]);
            }
        }
    }

    // ---- fused zero-fill: 3*128 non-idx rows in this block's span/columns
    {
        const floatx4 z = {0.f, 0.f, 0.f, 0.f};
        const int zr = tid >> 5;        // 0..7
        const int zc = tid & 31;        // float4 chunk within 128 cols
        #pragma unroll 4
        for (int p = 0; p < 48; ++p) {
            const int j = p * 8 + zr;   // 0..383
            const int q = j / 3, e = j % 3;
            const int delta = e + (e >= off ? 1 : 0);
            const long tok = (long)s * SEG_W + 4L * (mt * 128 + q) + delta;
            float* dst = obase + tok * D_MODEL + nt * 128 + zc * 4;
            __builtin_nontemporal_store(z, (floatx4*)dst);
        }
    }
}

extern "C" void kernel_launch(void* const* d_in, const int* in_sizes, int n_in,
                              void* d_out, int out_size, void* d_ws, size_t ws_size,
                              hipStream_t stream) {
    const float* x   = (const float*)d_in[0];
    const int*   hid = (const int*)d_in[1];
    float*       out = (float*)d_out;
    bf16_t* xg  = (bf16_t*)d_ws;
    bf16_t* xgT = xg + XG_ELEMS;
    bf16_t* S   = xgT + XG_ELEMS;     // total ws: 2*16.78 + 8.39 = 41.9 MB

    gather_kernel<<<dim3(2048), dim3(256), 0, stream>>>(x, hid, xg, xgT);
    qk_kernel<<<dim3(512), dim3(256), 0, stream>>>(xg, S);
    softmax_kernel<<<dim3(2048), dim3(256), 0, stream>>>(S);
    pv_kernel<<<dim3(512), dim3(256), 0, stream>>>(S, xgT, hid, out);
}